// Round 3
// baseline (279.668 us; speedup 1.0000x reference)
//
#include <hip/hip_runtime.h>
#include <hip/hip_bf16.h>
#include <stdint.h>

#define S_LEN 4096
#define E_DIM 2048
#define DH    128

typedef __bf16 bf16_t;
typedef bf16_t bf16x8 __attribute__((ext_vector_type(8)));
typedef float  f32x4  __attribute__((ext_vector_type(4)));

__device__ __forceinline__ unsigned short f2bf(float f) {
  union { float f; uint32_t u; } v; v.f = f;
  uint32_t u = v.u;
  uint32_t r = (u + 0x7fffu + ((u >> 16) & 1u)) >> 16;  // RNE
  return (unsigned short)r;
}

__device__ __forceinline__ bf16x8 ld_bf16x8(const unsigned short* p) {
  return *(const bf16x8*)p;
}

__device__ __forceinline__ f32x4 mfma16(bf16x8 a, bf16x8 b, f32x4 c) {
  return __builtin_amdgcn_mfma_f32_16x16x32_bf16(a, b, c, 0, 0, 0);
}

// async global->LDS, 16B per lane; ldst must be wave-uniform (lane*16 added by HW)
__device__ __forceinline__ void gload16(const void* gsrc, void* ldst) {
  __builtin_amdgcn_global_load_lds(
      (const __attribute__((address_space(1))) uint32_t*)gsrc,
      (__attribute__((address_space(3))) uint32_t*)ldst, 16, 0, 0);
}

// ---------------------------------------------------------------------------
// prep: trig table (cos,sin) [4096][64] + W^T bf16 [384][2048]
// ---------------------------------------------------------------------------
__global__ __launch_bounds__(256) void prep_kernel(
    const float* __restrict__ WQ, const float* __restrict__ WK,
    const float* __restrict__ WV,
    float2* __restrict__ trig, unsigned short* __restrict__ Wt)
{
  const int idx = blockIdx.x * 256 + threadIdx.x;
  if (idx < S_LEN * 64) {
    const int pos = idx >> 6, p = idx & 63;
    const float freq = powf(10000.0f, -(float)p / 64.0f);
    float sv, cv;
    sincosf((float)pos * freq, &sv, &cv);
    trig[idx] = make_float2(cv, sv);
  } else {
    const int j = idx - S_LEN * 64;          // 0 .. 3*128*2048-1
    const int n = j >> 11, k = j & 2047;     // n: output col (0..383)
    const int z = n >> 7, nl = n & 127;
    const float* W = (z == 0) ? WQ : ((z == 1) ? WK : WV);
    Wt[j] = f2bf(W[k * 128 + nl]);
  }
}

// ---------------------------------------------------------------------------
// proj v2: m97-structure GEMM.  BM=128, BN=96, BK=64.
// grid 512 (128 M-panels x 4 N-panels) = 2 blocks/CU. 256 thr, 4 waves (2Mx2N),
// wave tile 64x48 (4x3 subtiles). A staged as f32 via global_load_lds (32KB),
// B bf16 (12KB); source-swizzled so ds_read_b128 is conflict-free.
// ---------------------------------------------------------------------------
__global__ __launch_bounds__(256, 1) void proj_kernel(
    const float* __restrict__ x, const unsigned short* __restrict__ Wt,
    const float2* __restrict__ trig,
    unsigned short* __restrict__ Qb, unsigned short* __restrict__ Kb,
    unsigned short* __restrict__ Vt)
{
  __shared__ __align__(16) uint8_t Abuf[128 * 64 * 4];   // 32KB f32, swizzled
  __shared__ __align__(16) uint8_t Bbuf[96 * 64 * 2];    // 12KB bf16, swizzled

  const int tid  = threadIdx.x;
  const int lane = tid & 63, w2 = tid >> 6;      // wave 0..3
  const int wr = w2 & 1, wc = w2 >> 1;           // 2M x 2N wave grid
  const int col = lane & 15, kg = lane >> 4;

  const int bx = blockIdx.x;
  const int mp = bx >> 2;                        // M panel 0..127
  const int p  = bx & 3;                         // N panel 0..3 (96 cols)
  const int m0 = mp * 128;

  f32x4 acc[4][3];
  #pragma unroll
  for (int i = 0; i < 4; i++)
    #pragma unroll
    for (int j = 0; j < 3; j++) acc[i][j] = (f32x4){0.f, 0.f, 0.f, 0.f};

  const int arow_l  = lane >> 4;            // + c*16 + w2*4
  const int acolb_l = (lane & 15) * 16;
  const int brow_l  = lane >> 3;            // + c*32 + w2*8
  const int bcolb_l = (lane & 7) * 16;

  for (int k0 = 0; k0 < E_DIM; k0 += 64) {
    __syncthreads();                        // prev tile fully consumed
    // ---- stage A: 128 rows x 64 k f32, rows 256B, swizzle ^(row&15)<<4
    #pragma unroll
    for (int c = 0; c < 8; c++) {
      const int row   = c * 16 + w2 * 4 + arow_l;
      const int scolb = acolb_l ^ ((row & 15) << 4);
      gload16((const char*)x + ((size_t)(m0 + row) * E_DIM + k0) * 4 + scolb,
              Abuf + c * 4096 + w2 * 1024);
    }
    // ---- stage B: 96 rows x 64 k bf16, rows 128B, swizzle ^(row&7)<<4
    #pragma unroll
    for (int c = 0; c < 3; c++) {
      const int row   = c * 32 + w2 * 8 + brow_l;
      const int scolb = bcolb_l ^ ((row & 7) << 4);
      gload16((const char*)Wt + ((size_t)(p * 96 + row) * E_DIM + k0) * 2 + scolb,
              Bbuf + c * 4096 + w2 * 1024);
    }
    __syncthreads();                        // vmcnt drain + barrier: tile ready

    #pragma unroll
    for (int kk = 0; kk < 2; kk++) {
      bf16x8 af[4];
      #pragma unroll
      for (int i = 0; i < 4; i++) {
        const int row = wr * 64 + i * 16 + col;
        const int sw  = (row & 15) << 4;
        const int kb  = kk * 128 + kg * 32;
        float4 lo = *(const float4*)(Abuf + row * 256 + (kb ^ sw));
        float4 hi = *(const float4*)(Abuf + row * 256 + ((kb + 16) ^ sw));
        bf16x8 a;
        a[0] = (bf16_t)lo.x; a[1] = (bf16_t)lo.y;
        a[2] = (bf16_t)lo.z; a[3] = (bf16_t)lo.w;
        a[4] = (bf16_t)hi.x; a[5] = (bf16_t)hi.y;
        a[6] = (bf16_t)hi.z; a[7] = (bf16_t)hi.w;
        af[i] = a;
      }
      #pragma unroll
      for (int ns = 0; ns < 3; ns++) {
        const int n = wc * 48 + ns * 16 + col;
        bf16x8 bf = *(const bf16x8*)(Bbuf + n * 128 +
                                     ((kk * 64 + kg * 16) ^ ((n & 7) << 4)));
        #pragma unroll
        for (int i = 0; i < 4; i++)
          acc[i][ns] = mfma16(af[i], bf, acc[i][ns]);
      }
    }
  }

  // ---- epilogue: D layout col=lane&15 (n), row=(lane>>4)*4+r (m)
  #pragma unroll
  for (int i = 0; i < 4; i++) {
    const int mbase = m0 + wr * 64 + i * 16 + kg * 4;   // + r
    const int spos  = mbase & 4095;
    const int bb    = mbase >> 12;
    #pragma unroll
    for (int ns = 0; ns < 3; ns++) {
      const int n = p * 96 + wc * 48 + ns * 16 + col;
      const int z = n >> 7, d = n & 127;                // z uniform per subtile
      f32x4 v = acc[i][ns];
      if (z == 1) {                        // K: no rope
        #pragma unroll
        for (int r = 0; r < 4; r++)
          Kb[(size_t)(mbase + r) * DH + d] = f2bf(v[r]);
      } else {                             // Q or V: rope
        const float sgn  = (d & 1) ? 1.0f : -1.0f;
        const int   pidx = d >> 1;
        float ov[4];
        #pragma unroll
        for (int r = 0; r < 4; r++) {
          float  pv = __shfl_xor(v[r], 1, 64);
          float2 cs = trig[(spos + r) * 64 + pidx];
          ov[r] = v[r] * cs.x + sgn * pv * cs.y;
        }
        if (z == 0) {                      // Q: prescale by 1/sqrt(128)
          #pragma unroll
          for (int r = 0; r < 4; r++)
            Qb[(size_t)(mbase + r) * DH + d] =
                f2bf(ov[r] * 0.08838834764831845f);
        } else {                           // V: write transposed [b][d][s]
          ushort4 pk;
          pk.x = f2bf(ov[0]); pk.y = f2bf(ov[1]);
          pk.z = f2bf(ov[2]); pk.w = f2bf(ov[3]);
          *(ushort4*)(Vt + ((size_t)(bb * DH + d)) * S_LEN + spos) = pk;
        }
      }
    }
  }
}

// ---------------------------------------------------------------------------
// flash v2: QBLK=32, 2 waves/block, grid (128,4)=512 blocks (2+/CU, balanced)
// ---------------------------------------------------------------------------
__global__ __launch_bounds__(128, 1) void flash_kernel(
    const unsigned short* __restrict__ Qb, const unsigned short* __restrict__ Kb,
    const unsigned short* __restrict__ Vt, float* __restrict__ out)
{
  __shared__ __align__(16) unsigned short Ktile[64 * 128];   // swizzled
  __shared__ __align__(16) unsigned short Vtile[128 * 64];   // swizzled, d-major
  __shared__ __align__(16) unsigned short Plds[2][16][72];   // per-wave, padded

  const int b   = blockIdx.y;
  const int q0  = blockIdx.x * 32;
  const int tid = threadIdx.x;
  const int lane = tid & 63, w = tid >> 6;   // w in {0,1}
  const int col = lane & 15, kg = lane >> 4;

  // Q fragments: A layout row = lane&15, k = (lane>>4)*8+e (+32 per chunk)
  bf16x8 qf[4];
  {
    const unsigned short* qrow =
        Qb + (size_t)(b * S_LEN + q0 + w * 16 + col) * DH;
    #pragma unroll
    for (int kk = 0; kk < 4; kk++)
      qf[kk] = ld_bf16x8(qrow + kk * 32 + kg * 8);
  }

  f32x4 o[8];
  #pragma unroll
  for (int i = 0; i < 8; i++) o[i] = (f32x4){0.f, 0.f, 0.f, 0.f};
  float mrow[4] = {-1e30f, -1e30f, -1e30f, -1e30f};
  float lrow[4] = {0.f, 0.f, 0.f, 0.f};

  const unsigned short* Kbase = Kb + (size_t)b * S_LEN * DH;
  const unsigned short* Vbase = Vt + (size_t)b * DH * S_LEN;

  for (int kv0 = 0; kv0 < q0 + 32; kv0 += 64) {
    // ---- stage K [64][128] and Vt [128][64], XOR swizzle (row&7)<<4
    {
      const int kr  = tid >> 4;          // 0..7
      const int kcb = (tid & 15) * 16;
      #pragma unroll
      for (int rr = 0; rr < 8; rr++) {
        const int r = rr * 8 + kr;
        uint4 vv = *(const uint4*)(Kbase + (size_t)(kv0 + r) * DH + (tid & 15) * 8);
        *(uint4*)((char*)Ktile + r * 256 + (kcb ^ ((r & 7) << 4))) = vv;
      }
      const int vr  = tid >> 3;          // 0..15
      const int vcb = (tid & 7) * 16;
      #pragma unroll
      for (int rr = 0; rr < 8; rr++) {
        const int dD = rr * 16 + vr;
        uint4 vv = *(const uint4*)(Vbase + (size_t)dD * S_LEN + kv0 + (tid & 7) * 8);
        *(uint4*)((char*)Vtile + dD * 128 + (vcb ^ ((dD & 7) << 4))) = vv;
      }
    }
    __syncthreads();

    // ---- S = Q K^T
    f32x4 st[4];
    __builtin_amdgcn_s_setprio(1);
    #pragma unroll
    for (int kb = 0; kb < 4; kb++) {
      f32x4 sacc = (f32x4){0.f, 0.f, 0.f, 0.f};
      const int krow = kb * 16 + col;
      #pragma unroll
      for (int kk = 0; kk < 4; kk++) {
        bf16x8 kf = *(const bf16x8*)((const char*)Ktile + krow * 256 +
                                     ((kk * 64 + kg * 16) ^ ((krow & 7) << 4)));
        sacc = mfma16(qf[kk], kf, sacc);
      }
      st[kb] = sacc;
    }
    __builtin_amdgcn_s_setprio(0);

    // ---- causal mask (any tile overlapping the diagonal)
    if (kv0 + 63 > q0) {
      #pragma unroll
      for (int kb = 0; kb < 4; kb++) {
        const int key = kv0 + kb * 16 + col;
        #pragma unroll
        for (int r = 0; r < 4; r++) {
          const int q = q0 + w * 16 + kg * 4 + r;
          if (key > q) st[kb][r] = -1e30f;
        }
      }
    }

    // ---- online softmax (16-lane group reduce)
    float scale[4];
    #pragma unroll
    for (int r = 0; r < 4; r++) {
      float mx = fmaxf(fmaxf(st[0][r], st[1][r]), fmaxf(st[2][r], st[3][r]));
      #pragma unroll
      for (int off = 1; off < 16; off <<= 1)
        mx = fmaxf(mx, __shfl_xor(mx, off, 64));
      const float mnew = fmaxf(mrow[r], mx);
      scale[r] = __expf(mrow[r] - mnew);
      mrow[r] = mnew;
      float psum = 0.f;
      #pragma unroll
      for (int kb = 0; kb < 4; kb++) {
        float pexp = __expf(st[kb][r] - mnew);
        st[kb][r] = pexp;
        psum += pexp;
      }
      lrow[r] = lrow[r] * scale[r] + psum;
    }
    #pragma unroll
    for (int nt = 0; nt < 8; nt++)
      #pragma unroll
      for (int r = 0; r < 4; r++)
        o[nt][r] *= scale[r];

    // ---- P -> per-wave LDS (re-layout to A fragment)
    #pragma unroll
    for (int kb = 0; kb < 4; kb++)
      #pragma unroll
      for (int r = 0; r < 4; r++)
        Plds[w][kg * 4 + r][kb * 16 + col] = f2bf(st[kb][r]);

    // ---- O += P V
    __builtin_amdgcn_s_setprio(1);
    #pragma unroll
    for (int kc = 0; kc < 2; kc++) {
      bf16x8 pa = ld_bf16x8(&Plds[w][col][kc * 32 + kg * 8]);
      #pragma unroll
      for (int nt = 0; nt < 8; nt++) {
        const int vrow = nt * 16 + col;
        bf16x8 vf = *(const bf16x8*)((const char*)Vtile + vrow * 128 +
                                     ((kc * 64 + kg * 16) ^ ((vrow & 7) << 4)));
        o[nt] = mfma16(pa, vf, o[nt]);
      }
    }
    __builtin_amdgcn_s_setprio(0);
    __syncthreads();
  }

  // ---- finalize
  float inv[4];
  #pragma unroll
  for (int r = 0; r < 4; r++) {
    float l = lrow[r];
    #pragma unroll
    for (int off = 1; off < 16; off <<= 1)
      l += __shfl_xor(l, off, 64);
    inv[r] = 1.0f / l;
  }
  float* orow = out + (size_t)(b * S_LEN + q0 + w * 16 + kg * 4) * DH;
  #pragma unroll
  for (int nt = 0; nt < 8; nt++)
    #pragma unroll
    for (int r = 0; r < 4; r++)
      orow[r * DH + nt * 16 + col] = o[nt][r] * inv[r];
}

// ---------------------------------------------------------------------------
extern "C" void kernel_launch(void* const* d_in, const int* in_sizes, int n_in,
                              void* d_out, int out_size, void* d_ws, size_t ws_size,
                              hipStream_t stream) {
  const float* x  = (const float*)d_in[0];
  const float* WQ = (const float*)d_in[1];
  const float* WK = (const float*)d_in[2];
  const float* WV = (const float*)d_in[3];
  float* out = (float*)d_out;

  char* ws = (char*)d_ws;
  float2*         trig = (float2*)(ws);                      // 2 MB
  unsigned short* Wt   = (unsigned short*)(ws + (2u << 20)); // 1.5 MB
  unsigned short* Qb   = (unsigned short*)(ws + (4u << 20)); // 4 MB
  unsigned short* Kb   = (unsigned short*)(ws + (8u << 20)); // 4 MB
  unsigned short* Vt   = (unsigned short*)(ws + (12u << 20));// 4 MB (ends 16MB)

  hipLaunchKernelGGL(prep_kernel, dim3(4096), dim3(256), 0, stream,
                     WQ, WK, WV, trig, Wt);
  hipLaunchKernelGGL(proj_kernel, dim3(512), dim3(256), 0, stream,
                     x, Wt, trig, Qb, Kb, Vt);
  hipLaunchKernelGGL(flash_kernel, dim3(128, 4), dim3(256 / 2), 0, stream,
                     Qb, Kb, Vt, out);
}

// Round 5
// 200.145 us; speedup vs baseline: 1.3973x; 1.3973x over previous
//
#include <hip/hip_runtime.h>
#include <hip/hip_bf16.h>
#include <stdint.h>

#define S_LEN 4096
#define E_DIM 2048
#define DH    128

typedef __bf16 bf16_t;
typedef bf16_t bf16x8 __attribute__((ext_vector_type(8)));
typedef float  f32x4  __attribute__((ext_vector_type(4)));

__device__ __forceinline__ unsigned short f2bf(float f) {
  union { float f; uint32_t u; } v; v.f = f;
  uint32_t u = v.u;
  uint32_t r = (u + 0x7fffu + ((u >> 16) & 1u)) >> 16;  // RNE
  return (unsigned short)r;
}

__device__ __forceinline__ bf16x8 ld_bf16x8(const unsigned short* p) {
  return *(const bf16x8*)p;
}

__device__ __forceinline__ f32x4 mfma16(bf16x8 a, bf16x8 b, f32x4 c) {
  return __builtin_amdgcn_mfma_f32_16x16x32_bf16(a, b, c, 0, 0, 0);
}

// async global->LDS, 16B/lane; LDS dest wave-uniform (HW adds lane*16)
__device__ __forceinline__ void gload16(const void* gsrc, void* ldst) {
  __builtin_amdgcn_global_load_lds(
      (const __attribute__((address_space(1))) uint32_t*)gsrc,
      (__attribute__((address_space(3))) uint32_t*)ldst, 16, 0, 0);
}

// ---------------------------------------------------------------------------
// prep: trig [4096][64] (blocks 0..1023) + coalesced W^T transpose (192 tiles)
// ---------------------------------------------------------------------------
__global__ __launch_bounds__(256) void prep_kernel(
    const float* __restrict__ WQ, const float* __restrict__ WK,
    const float* __restrict__ WV,
    float2* __restrict__ trig, unsigned short* __restrict__ Wt)
{
  const int bx  = blockIdx.x;
  const int tid = threadIdx.x;
  if (bx < 1024) {
    const int idx = bx * 256 + tid;            // 0 .. 262143
    const int pos = idx >> 6, p = idx & 63;
    const float freq = powf(10000.0f, -(float)p / 64.0f);
    float sv, cv;
    sincosf((float)pos * freq, &sv, &cv);
    trig[idx] = make_float2(cv, sv);
    return;
  }
  // ---- transpose W[z] (2048 k x 128 n) -> Wt[z*128+n][k], 64x64 tiles
  __shared__ float lds[64][65];
  const int t   = bx - 1024;                   // 0..191
  const int z   = t >> 6;
  const int rem = t & 63;
  const int k0  = (rem >> 1) * 64;
  const int n0  = (rem & 1) * 64;
  const float* W = (z == 0) ? WQ : ((z == 1) ? WK : WV);
  #pragma unroll
  for (int pass = 0; pass < 4; pass++) {
    const int r  = pass * 16 + (tid >> 4);
    const int c4 = (tid & 15) * 4;
    float4 v = *(const float4*)(W + (size_t)(k0 + r) * 128 + n0 + c4);
    lds[c4 + 0][r] = v.x; lds[c4 + 1][r] = v.y;
    lds[c4 + 2][r] = v.z; lds[c4 + 3][r] = v.w;
  }
  __syncthreads();
  #pragma unroll
  for (int pass = 0; pass < 4; pass++) {
    const int n  = pass * 16 + (tid >> 4);
    const int k4 = (tid & 15) * 4;
    ushort4 pk;
    pk.x = f2bf(lds[n][k4 + 0]); pk.y = f2bf(lds[n][k4 + 1]);
    pk.z = f2bf(lds[n][k4 + 2]); pk.w = f2bf(lds[n][k4 + 3]);
    *(ushort4*)(Wt + (size_t)(z * 128 + n0 + n) * E_DIM + k0 + k4) = pk;
  }
}

// ---------------------------------------------------------------------------
// proj v3: BM=128, BN=96, BK=32, 2-phase double-buffer.
// grid (128 mp, 4 p): same-mp blocks 128 apart -> same XCD (share x in L2).
// 256 thr, 4 waves (2M x 2N), wave tile 64x48. LDS 44KB -> 3 blocks/CU.
// ---------------------------------------------------------------------------
__global__ __launch_bounds__(256, 3) void proj_kernel(
    const float* __restrict__ x, const unsigned short* __restrict__ Wt,
    const float2* __restrict__ trig,
    unsigned short* __restrict__ Qb, unsigned short* __restrict__ Kb,
    unsigned short* __restrict__ Vt)
{
  __shared__ __align__(16) uint8_t Abuf[2 * 128 * 128];  // f32, 128B rows, swz
  __shared__ __align__(16) uint8_t Bbuf[2 * 96 * 64];    // bf16, 64B rows, swz

  const int tid  = threadIdx.x;
  const int lane = tid & 63, w2 = tid >> 6;
  const int wr = w2 & 1, wc = w2 >> 1;
  const int col = lane & 15, kg = lane >> 4;

  const int m0 = blockIdx.x * 128;
  const int p  = blockIdx.y;

  f32x4 acc[4][3];
  #pragma unroll
  for (int i = 0; i < 4; i++)
    #pragma unroll
    for (int j = 0; j < 3; j++) acc[i][j] = (f32x4){0.f, 0.f, 0.f, 0.f};

  // staging lane geometry
  const int ar  = lane >> 3;            // 0..7   (A: 8 rows/call)
  const int acb = (lane & 7) * 16;      // A byte col 0..112
  const int br  = lane >> 2;            // 0..15  (B: 16 rows/call)
  const int bcb = (lane & 3) * 16;      // B byte col 0..48

  #define STAGE(K0, BUF)                                                      \
    do {                                                                      \
      uint8_t* Ad = Abuf + (BUF) * 16384 + w2 * 4096;                         \
      _Pragma("unroll")                                                       \
      for (int c = 0; c < 4; c++) {                                           \
        const int row = w2 * 32 + c * 8 + ar;                                 \
        const int src = acb ^ ((row & 7) << 4);                               \
        gload16((const char*)x + ((size_t)(m0 + row) * E_DIM + (K0)) * 4 + src,\
                Ad + c * 1024);                                               \
      }                                                                       \
      _Pragma("unroll")                                                       \
      for (int c = 0; c < 6; c++) {                                           \
        if ((c & 3) == w2) {                                                  \
          const int row = c * 16 + br;                                        \
          const int src = bcb ^ ((row & 3) << 4);                             \
          gload16((const char*)Wt +                                           \
                      ((size_t)(p * 96 + row) * E_DIM + (K0)) * 2 + src,      \
                  Bbuf + (BUF) * 6144 + c * 1024);                            \
        }                                                                     \
      }                                                                       \
    } while (0)

  STAGE(0, 0);
  __syncthreads();

  int cur = 0;
  for (int t = 0; t < 64; t++) {
    if (t < 63) STAGE((t + 1) * 32, cur ^ 1);

    const uint8_t* Ab = Abuf + cur * 16384;
    const uint8_t* Bb = Bbuf + cur * 6144;

    bf16x8 af[4];
    #pragma unroll
    for (int i = 0; i < 4; i++) {
      const int row = wr * 64 + i * 16 + col;
      const int sw  = (row & 7) << 4;
      float4 lo = *(const float4*)(Ab + row * 128 + ((kg * 32) ^ sw));
      float4 hi = *(const float4*)(Ab + row * 128 + ((kg * 32 + 16) ^ sw));
      bf16x8 a;
      a[0] = (bf16_t)lo.x; a[1] = (bf16_t)lo.y;
      a[2] = (bf16_t)lo.z; a[3] = (bf16_t)lo.w;
      a[4] = (bf16_t)hi.x; a[5] = (bf16_t)hi.y;
      a[6] = (bf16_t)hi.z; a[7] = (bf16_t)hi.w;
      af[i] = a;
    }
    __builtin_amdgcn_s_setprio(1);
    #pragma unroll
    for (int ns = 0; ns < 3; ns++) {
      const int n = wc * 48 + ns * 16 + col;
      bf16x8 bf = *(const bf16x8*)(Bb + n * 64 + ((kg * 16) ^ ((n & 3) << 4)));
      #pragma unroll
      for (int i = 0; i < 4; i++)
        acc[i][ns] = mfma16(af[i], bf, acc[i][ns]);
    }
    __builtin_amdgcn_s_setprio(0);
    __syncthreads();         // drains vmcnt -> tile t+1 ready; buf[cur] free
    cur ^= 1;
  }
  #undef STAGE

  // ---- epilogue: D layout col=lane&15 (n), row=(lane>>4)*4+r (m)
  #pragma unroll
  for (int i = 0; i < 4; i++) {
    const int mbase = m0 + wr * 64 + i * 16 + kg * 4;
    const int spos  = mbase & 4095;
    const int bb    = mbase >> 12;
    #pragma unroll
    for (int ns = 0; ns < 3; ns++) {
      const int n = p * 96 + wc * 48 + ns * 16 + col;
      const int z = n >> 7, d = n & 127;
      f32x4 v = acc[i][ns];
      if (z == 1) {                        // K: no rope
        #pragma unroll
        for (int r = 0; r < 4; r++)
          Kb[(size_t)(mbase + r) * DH + d] = f2bf(v[r]);
      } else {                             // Q or V: rope
        const float sgn  = (d & 1) ? 1.0f : -1.0f;
        const int   pidx = d >> 1;
        float ov[4];
        #pragma unroll
        for (int r = 0; r < 4; r++) {
          float  pv = __shfl_xor(v[r], 1, 64);
          float2 cs = trig[(spos + r) * 64 + pidx];
          ov[r] = v[r] * cs.x + sgn * pv * cs.y;
        }
        if (z == 0) {                      // Q: prescale by 1/sqrt(128)
          #pragma unroll
          for (int r = 0; r < 4; r++)
            Qb[(size_t)(mbase + r) * DH + d] =
                f2bf(ov[r] * 0.08838834764831845f);
        } else {                           // V: write transposed [b][d][s]
          ushort4 pk;
          pk.x = f2bf(ov[0]); pk.y = f2bf(ov[1]);
          pk.z = f2bf(ov[2]); pk.w = f2bf(ov[3]);
          *(ushort4*)(Vt + ((size_t)(bb * DH + d)) * S_LEN + spos) = pk;
        }
      }
    }
  }
}

// ---------------------------------------------------------------------------
// flash (round-3 verbatim, known-good): QBLK=32, 2 waves, grid (128,4)
// ---------------------------------------------------------------------------
__global__ __launch_bounds__(128, 1) void flash_kernel(
    const unsigned short* __restrict__ Qb, const unsigned short* __restrict__ Kb,
    const unsigned short* __restrict__ Vt, float* __restrict__ out)
{
  __shared__ __align__(16) unsigned short Ktile[64 * 128];   // swizzled
  __shared__ __align__(16) unsigned short Vtile[128 * 64];   // swizzled, d-major
  __shared__ __align__(16) unsigned short Plds[2][16][72];   // per-wave, padded

  const int b   = blockIdx.y;
  const int q0  = blockIdx.x * 32;
  const int tid = threadIdx.x;
  const int lane = tid & 63, w = tid >> 6;   // w in {0,1}
  const int col = lane & 15, kg = lane >> 4;

  // Q fragments: A layout row = lane&15, k = (lane>>4)*8+e (+32 per chunk)
  bf16x8 qf[4];
  {
    const unsigned short* qrow =
        Qb + (size_t)(b * S_LEN + q0 + w * 16 + col) * DH;
    #pragma unroll
    for (int kk = 0; kk < 4; kk++)
      qf[kk] = ld_bf16x8(qrow + kk * 32 + kg * 8);
  }

  f32x4 o[8];
  #pragma unroll
  for (int i = 0; i < 8; i++) o[i] = (f32x4){0.f, 0.f, 0.f, 0.f};
  float mrow[4] = {-1e30f, -1e30f, -1e30f, -1e30f};
  float lrow[4] = {0.f, 0.f, 0.f, 0.f};

  const unsigned short* Kbase = Kb + (size_t)b * S_LEN * DH;
  const unsigned short* Vbase = Vt + (size_t)b * DH * S_LEN;

  for (int kv0 = 0; kv0 < q0 + 32; kv0 += 64) {
    // ---- stage K [64][128] and Vt [128][64], XOR swizzle (row&7)<<4
    {
      const int kr  = tid >> 4;          // 0..7
      const int kcb = (tid & 15) * 16;
      #pragma unroll
      for (int rr = 0; rr < 8; rr++) {
        const int r = rr * 8 + kr;
        uint4 vv = *(const uint4*)(Kbase + (size_t)(kv0 + r) * DH + (tid & 15) * 8);
        *(uint4*)((char*)Ktile + r * 256 + (kcb ^ ((r & 7) << 4))) = vv;
      }
      const int vr  = tid >> 3;          // 0..15
      const int vcb = (tid & 7) * 16;
      #pragma unroll
      for (int rr = 0; rr < 8; rr++) {
        const int dD = rr * 16 + vr;
        uint4 vv = *(const uint4*)(Vbase + (size_t)dD * S_LEN + kv0 + (tid & 7) * 8);
        *(uint4*)((char*)Vtile + dD * 128 + (vcb ^ ((dD & 7) << 4))) = vv;
      }
    }
    __syncthreads();

    // ---- S = Q K^T
    f32x4 st[4];
    __builtin_amdgcn_s_setprio(1);
    #pragma unroll
    for (int kb = 0; kb < 4; kb++) {
      f32x4 sacc = (f32x4){0.f, 0.f, 0.f, 0.f};
      const int krow = kb * 16 + col;
      #pragma unroll
      for (int kk = 0; kk < 4; kk++) {
        bf16x8 kf = *(const bf16x8*)((const char*)Ktile + krow * 256 +
                                     ((kk * 64 + kg * 16) ^ ((krow & 7) << 4)));
        sacc = mfma16(qf[kk], kf, sacc);
      }
      st[kb] = sacc;
    }
    __builtin_amdgcn_s_setprio(0);

    // ---- causal mask (any tile overlapping the diagonal)
    if (kv0 + 63 > q0) {
      #pragma unroll
      for (int kb = 0; kb < 4; kb++) {
        const int key = kv0 + kb * 16 + col;
        #pragma unroll
        for (int r = 0; r < 4; r++) {
          const int q = q0 + w * 16 + kg * 4 + r;
          if (key > q) st[kb][r] = -1e30f;
        }
      }
    }

    // ---- online softmax (16-lane group reduce)
    float scale[4];
    #pragma unroll
    for (int r = 0; r < 4; r++) {
      float mx = fmaxf(fmaxf(st[0][r], st[1][r]), fmaxf(st[2][r], st[3][r]));
      #pragma unroll
      for (int off = 1; off < 16; off <<= 1)
        mx = fmaxf(mx, __shfl_xor(mx, off, 64));
      const float mnew = fmaxf(mrow[r], mx);
      scale[r] = __expf(mrow[r] - mnew);
      mrow[r] = mnew;
      float psum = 0.f;
      #pragma unroll
      for (int kb = 0; kb < 4; kb++) {
        float pexp = __expf(st[kb][r] - mnew);
        st[kb][r] = pexp;
        psum += pexp;
      }
      lrow[r] = lrow[r] * scale[r] + psum;
    }
    #pragma unroll
    for (int nt = 0; nt < 8; nt++)
      #pragma unroll
      for (int r = 0; r < 4; r++)
        o[nt][r] *= scale[r];

    // ---- P -> per-wave LDS (re-layout to A fragment)
    #pragma unroll
    for (int kb = 0; kb < 4; kb++)
      #pragma unroll
      for (int r = 0; r < 4; r++)
        Plds[w][kg * 4 + r][kb * 16 + col] = f2bf(st[kb][r]);

    // ---- O += P V
    __builtin_amdgcn_s_setprio(1);
    #pragma unroll
    for (int kc = 0; kc < 2; kc++) {
      bf16x8 pa = ld_bf16x8(&Plds[w][col][kc * 32 + kg * 8]);
      #pragma unroll
      for (int nt = 0; nt < 8; nt++) {
        const int vrow = nt * 16 + col;
        bf16x8 vf = *(const bf16x8*)((const char*)Vtile + vrow * 128 +
                                     ((kc * 64 + kg * 16) ^ ((vrow & 7) << 4)));
        o[nt] = mfma16(pa, vf, o[nt]);
      }
    }
    __builtin_amdgcn_s_setprio(0);
    __syncthreads();
  }

  // ---- finalize
  float inv[4];
  #pragma unroll
  for (int r = 0; r < 4; r++) {
    float l = lrow[r];
    #pragma unroll
    for (int off = 1; off < 16; off <<= 1)
      l += __shfl_xor(l, off, 64);
    inv[r] = 1.0f / l;
  }
  float* orow = out + (size_t)(b * S_LEN + q0 + w * 16 + kg * 4) * DH;
  #pragma unroll
  for (int nt = 0; nt < 8; nt++)
    #pragma unroll
    for (int r = 0; r < 4; r++)
      orow[r * DH + nt * 16 + col] = o[nt][r] * inv[r];
}

// ---------------------------------------------------------------------------
extern "C" void kernel_launch(void* const* d_in, const int* in_sizes, int n_in,
                              void* d_out, int out_size, void* d_ws, size_t ws_size,
                              hipStream_t stream) {
  const float* x  = (const float*)d_in[0];
  const float* WQ = (const float*)d_in[1];
  const float* WK = (const float*)d_in[2];
  const float* WV = (const float*)d_in[3];
  float* out = (float*)d_out;

  char* ws = (char*)d_ws;
  float2*         trig = (float2*)(ws);                      // 2 MB
  unsigned short* Wt   = (unsigned short*)(ws + (2u << 20)); // 1.5 MB
  unsigned short* Qb   = (unsigned short*)(ws + (4u << 20)); // 4 MB
  unsigned short* Kb   = (unsigned short*)(ws + (8u << 20)); // 4 MB
  unsigned short* Vt   = (unsigned short*)(ws + (12u << 20));// 4 MB (ends 16MB)

  hipLaunchKernelGGL(prep_kernel, dim3(1216), dim3(256), 0, stream,
                     WQ, WK, WV, trig, Wt);
  hipLaunchKernelGGL(proj_kernel, dim3(128, 4), dim3(256), 0, stream,
                     x, Wt, trig, Qb, Kb, Vt);
  hipLaunchKernelGGL(flash_kernel, dim3(128, 4), dim3(128), 0, stream,
                     Qb, Kb, Vt, out);
}

// Round 6
// 142.444 us; speedup vs baseline: 1.9634x; 1.4051x over previous
//
#include <hip/hip_runtime.h>
#include <hip/hip_bf16.h>
#include <stdint.h>

#define S_LEN 4096
#define E_DIM 2048
#define DH    128

typedef __bf16 bf16_t;
typedef bf16_t bf16x8 __attribute__((ext_vector_type(8)));
typedef float  f32x4  __attribute__((ext_vector_type(4)));

__device__ __forceinline__ unsigned short f2bf(float f) {
  union { float f; uint32_t u; } v; v.f = f;
  uint32_t u = v.u;
  uint32_t r = (u + 0x7fffu + ((u >> 16) & 1u)) >> 16;  // RNE
  return (unsigned short)r;
}

__device__ __forceinline__ bf16x8 ld_bf16x8(const unsigned short* p) {
  return *(const bf16x8*)p;
}

__device__ __forceinline__ f32x4 mfma16(bf16x8 a, bf16x8 b, f32x4 c) {
  return __builtin_amdgcn_mfma_f32_16x16x32_bf16(a, b, c, 0, 0, 0);
}

// async global->LDS, 16B/lane; LDS dest wave-uniform (HW adds lane*16)
__device__ __forceinline__ void gload16(const void* gsrc, void* ldst) {
  __builtin_amdgcn_global_load_lds(
      (const __attribute__((address_space(1))) uint32_t*)gsrc,
      (__attribute__((address_space(3))) uint32_t*)ldst, 16, 0, 0);
}

// ---------------------------------------------------------------------------
// prep: trig [4096][64] (blocks 0..1023) + coalesced W^T transpose (192 tiles)
// ---------------------------------------------------------------------------
__global__ __launch_bounds__(256) void prep_kernel(
    const float* __restrict__ WQ, const float* __restrict__ WK,
    const float* __restrict__ WV,
    float2* __restrict__ trig, unsigned short* __restrict__ Wt)
{
  const int bx  = blockIdx.x;
  const int tid = threadIdx.x;
  if (bx < 1024) {
    const int idx = bx * 256 + tid;            // 0 .. 262143
    const int pos = idx >> 6, p = idx & 63;
    const float freq = powf(10000.0f, -(float)p / 64.0f);
    float sv, cv;
    sincosf((float)pos * freq, &sv, &cv);
    trig[idx] = make_float2(cv, sv);
    return;
  }
  // ---- transpose W[z] (2048 k x 128 n) -> Wt[z*128+n][k], 64x64 tiles
  __shared__ float lds[64][65];
  const int t   = bx - 1024;                   // 0..191
  const int z   = t >> 6;
  const int rem = t & 63;
  const int k0  = (rem >> 1) * 64;
  const int n0  = (rem & 1) * 64;
  const float* W = (z == 0) ? WQ : ((z == 1) ? WK : WV);
  #pragma unroll
  for (int pass = 0; pass < 4; pass++) {
    const int r  = pass * 16 + (tid >> 4);
    const int c4 = (tid & 15) * 4;
    float4 v = *(const float4*)(W + (size_t)(k0 + r) * 128 + n0 + c4);
    lds[c4 + 0][r] = v.x; lds[c4 + 1][r] = v.y;
    lds[c4 + 2][r] = v.z; lds[c4 + 3][r] = v.w;
  }
  __syncthreads();
  #pragma unroll
  for (int pass = 0; pass < 4; pass++) {
    const int n  = pass * 16 + (tid >> 4);
    const int k4 = (tid & 15) * 4;
    ushort4 pk;
    pk.x = f2bf(lds[n][k4 + 0]); pk.y = f2bf(lds[n][k4 + 1]);
    pk.z = f2bf(lds[n][k4 + 2]); pk.w = f2bf(lds[n][k4 + 3]);
    *(ushort4*)(Wt + (size_t)(z * 128 + n0 + n) * E_DIM + k0 + k4) = pk;
  }
}

// ---------------------------------------------------------------------------
// proj v3 (unchanged, passed r5): BM=128, BN=96, BK=32, 2-phase double-buffer.
// ---------------------------------------------------------------------------
__global__ __launch_bounds__(256, 3) void proj_kernel(
    const float* __restrict__ x, const unsigned short* __restrict__ Wt,
    const float2* __restrict__ trig,
    unsigned short* __restrict__ Qb, unsigned short* __restrict__ Kb,
    unsigned short* __restrict__ Vt)
{
  __shared__ __align__(16) uint8_t Abuf[2 * 128 * 128];  // f32, 128B rows, swz
  __shared__ __align__(16) uint8_t Bbuf[2 * 96 * 64];    // bf16, 64B rows, swz

  const int tid  = threadIdx.x;
  const int lane = tid & 63, w2 = tid >> 6;
  const int wr = w2 & 1, wc = w2 >> 1;
  const int col = lane & 15, kg = lane >> 4;

  const int m0 = blockIdx.x * 128;
  const int p  = blockIdx.y;

  f32x4 acc[4][3];
  #pragma unroll
  for (int i = 0; i < 4; i++)
    #pragma unroll
    for (int j = 0; j < 3; j++) acc[i][j] = (f32x4){0.f, 0.f, 0.f, 0.f};

  const int ar  = lane >> 3;            // 0..7   (A: 8 rows/call)
  const int acb = (lane & 7) * 16;      // A byte col 0..112
  const int br  = lane >> 2;            // 0..15  (B: 16 rows/call)
  const int bcb = (lane & 3) * 16;      // B byte col 0..48

  #define STAGE(K0, BUF)                                                      \
    do {                                                                      \
      uint8_t* Ad = Abuf + (BUF) * 16384 + w2 * 4096;                         \
      _Pragma("unroll")                                                       \
      for (int c = 0; c < 4; c++) {                                           \
        const int row = w2 * 32 + c * 8 + ar;                                 \
        const int src = acb ^ ((row & 7) << 4);                               \
        gload16((const char*)x + ((size_t)(m0 + row) * E_DIM + (K0)) * 4 + src,\
                Ad + c * 1024);                                               \
      }                                                                       \
      _Pragma("unroll")                                                       \
      for (int c = 0; c < 6; c++) {                                           \
        if ((c & 3) == w2) {                                                  \
          const int row = c * 16 + br;                                        \
          const int src = bcb ^ ((row & 3) << 4);                             \
          gload16((const char*)Wt +                                           \
                      ((size_t)(p * 96 + row) * E_DIM + (K0)) * 2 + src,      \
                  Bbuf + (BUF) * 6144 + c * 1024);                            \
        }                                                                     \
      }                                                                       \
    } while (0)

  STAGE(0, 0);
  __syncthreads();

  int cur = 0;
  for (int t = 0; t < 64; t++) {
    if (t < 63) STAGE((t + 1) * 32, cur ^ 1);

    const uint8_t* Ab = Abuf + cur * 16384;
    const uint8_t* Bb = Bbuf + cur * 6144;

    bf16x8 af[4];
    #pragma unroll
    for (int i = 0; i < 4; i++) {
      const int row = wr * 64 + i * 16 + col;
      const int sw  = (row & 7) << 4;
      float4 lo = *(const float4*)(Ab + row * 128 + ((kg * 32) ^ sw));
      float4 hi = *(const float4*)(Ab + row * 128 + ((kg * 32 + 16) ^ sw));
      bf16x8 a;
      a[0] = (bf16_t)lo.x; a[1] = (bf16_t)lo.y;
      a[2] = (bf16_t)lo.z; a[3] = (bf16_t)lo.w;
      a[4] = (bf16_t)hi.x; a[5] = (bf16_t)hi.y;
      a[6] = (bf16_t)hi.z; a[7] = (bf16_t)hi.w;
      af[i] = a;
    }
    __builtin_amdgcn_s_setprio(1);
    #pragma unroll
    for (int ns = 0; ns < 3; ns++) {
      const int n = wc * 48 + ns * 16 + col;
      bf16x8 bf = *(const bf16x8*)(Bb + n * 64 + ((kg * 16) ^ ((n & 3) << 4)));
      #pragma unroll
      for (int i = 0; i < 4; i++)
        acc[i][ns] = mfma16(af[i], bf, acc[i][ns]);
    }
    __builtin_amdgcn_s_setprio(0);
    __syncthreads();         // drains vmcnt -> tile t+1 ready; buf[cur] free
    cur ^= 1;
  }
  #undef STAGE

  // ---- epilogue: D layout col=lane&15 (n), row=(lane>>4)*4+r (m)
  #pragma unroll
  for (int i = 0; i < 4; i++) {
    const int mbase = m0 + wr * 64 + i * 16 + kg * 4;
    const int spos  = mbase & 4095;
    const int bb    = mbase >> 12;
    #pragma unroll
    for (int ns = 0; ns < 3; ns++) {
      const int n = p * 96 + wc * 48 + ns * 16 + col;
      const int z = n >> 7, d = n & 127;
      f32x4 v = acc[i][ns];
      if (z == 1) {                        // K: no rope
        #pragma unroll
        for (int r = 0; r < 4; r++)
          Kb[(size_t)(mbase + r) * DH + d] = f2bf(v[r]);
      } else {                             // Q or V: rope
        const float sgn  = (d & 1) ? 1.0f : -1.0f;
        const int   pidx = d >> 1;
        float ov[4];
        #pragma unroll
        for (int r = 0; r < 4; r++) {
          float  pv = __shfl_xor(v[r], 1, 64);
          float2 cs = trig[(spos + r) * 64 + pidx];
          ov[r] = v[r] * cs.x + sgn * pv * cs.y;
        }
        if (z == 0) {                      // Q: prescale by 1/sqrt(128)
          #pragma unroll
          for (int r = 0; r < 4; r++)
            Qb[(size_t)(mbase + r) * DH + d] =
                f2bf(ov[r] * 0.08838834764831845f);
        } else {                           // V: write transposed [b][d][s]
          ushort4 pk;
          pk.x = f2bf(ov[0]); pk.y = f2bf(ov[1]);
          pk.z = f2bf(ov[2]); pk.w = f2bf(ov[3]);
          *(ushort4*)(Vt + ((size_t)(bb * DH + d)) * S_LEN + spos) = pk;
        }
      }
    }
  }
}

// ---------------------------------------------------------------------------
// flash v4: QBLK=32, KVBLK=128 over wave pairs (4 waves). 512 blocks, LDS 73KB
// -> 2 blocks/CU, 8 waves/CU. Complementary block pairing for causal balance.
// Fix vs r4: lrow 16-lane reduce BEFORE the LSE merge (r4 normalized by l/16).
// ---------------------------------------------------------------------------
__global__ __launch_bounds__(256, 2) void flash_kernel(
    const unsigned short* __restrict__ Qb, const unsigned short* __restrict__ Kb,
    const unsigned short* __restrict__ Vt, float* __restrict__ out)
{
  __shared__ __align__(16) unsigned short Ktile[128 * 128];  // [kv][d] swz
  __shared__ __align__(16) unsigned short Vtile[128 * 128];  // [d][kv] swz
  __shared__ __align__(16) unsigned short Plds[4][16][72];

  // complementary pairing: co-resident blocks (bid, bid+256) have work
  // summing ~const; batch from low bit / half.
  const int bid  = blockIdx.x;
  const int half = bid >> 8, rb = bid & 255;
  const int qi   = half ? (127 - (rb >> 1)) : (rb >> 1);
  const int b    = (rb & 1) | (half << 1);
  const int q0   = qi * 32;

  const int tid = threadIdx.x;
  const int lane = tid & 63, w = tid >> 6;
  const int h   = w & 1;        // q half (16 rows)
  const int kvh = w >> 1;       // kv half (64 keys)
  const int col = lane & 15, kg = lane >> 4;

  bf16x8 qf[4];
  {
    const unsigned short* qrow =
        Qb + (size_t)(b * S_LEN + q0 + h * 16 + col) * DH;
    #pragma unroll
    for (int kk = 0; kk < 4; kk++)
      qf[kk] = ld_bf16x8(qrow + kk * 32 + kg * 8);
  }

  f32x4 o[8];
  #pragma unroll
  for (int i = 0; i < 8; i++) o[i] = (f32x4){0.f, 0.f, 0.f, 0.f};
  float mrow[4] = {-1e30f, -1e30f, -1e30f, -1e30f};
  float lrow[4] = {0.f, 0.f, 0.f, 0.f};

  const char* Kbase = (const char*)(Kb + (size_t)b * S_LEN * DH);
  const char* Vbase = (const char*)(Vt + (size_t)b * DH * S_LEN);

  const int r_off = lane >> 4, colb = (lane & 15) * 16;

  for (int kv0 = 0; kv0 < q0 + 32; kv0 += 128) {
    // ---- stage K[128][128] + V[128 d][128 kv] via source-swizzled gload_lds
    #pragma unroll
    for (int c = 0; c < 8; c++) {
      const int row = w * 32 + c * 4 + r_off;           // kv index
      const int src = colb ^ ((row & 7) << 4);
      gload16(Kbase + (size_t)(kv0 + row) * 256 + src,
              (char*)Ktile + w * 8192 + c * 1024);
    }
    #pragma unroll
    for (int c = 0; c < 8; c++) {
      const int d   = w * 32 + c * 4 + r_off;           // head-dim index
      const int src = colb ^ ((d & 7) << 4);
      gload16(Vbase + (size_t)d * 8192 + (size_t)kv0 * 2 + src,
              (char*)Vtile + w * 8192 + c * 1024);
    }
    __syncthreads();

    // ---- S = Q K^T over this wave's 64 keys
    f32x4 st[4];
    __builtin_amdgcn_s_setprio(1);
    #pragma unroll
    for (int kb = 0; kb < 4; kb++) {
      f32x4 sacc = (f32x4){0.f, 0.f, 0.f, 0.f};
      const int krow = kvh * 64 + kb * 16 + col;
      #pragma unroll
      for (int kk = 0; kk < 4; kk++) {
        bf16x8 kf = *(const bf16x8*)((const char*)Ktile + krow * 256 +
                                     ((kk * 64 + kg * 16) ^ ((krow & 7) << 4)));
        sacc = mfma16(qf[kk], kf, sacc);
      }
      st[kb] = sacc;
    }
    __builtin_amdgcn_s_setprio(0);

    // ---- causal mask
    if (kv0 + 127 > q0) {
      #pragma unroll
      for (int kb = 0; kb < 4; kb++) {
        const int key = kv0 + kvh * 64 + kb * 16 + col;
        #pragma unroll
        for (int r = 0; r < 4; r++) {
          const int q = q0 + h * 16 + kg * 4 + r;
          if (key > q) st[kb][r] = -1e30f;
        }
      }
    }

    // ---- online softmax (16-lane group reduce; mrow group-uniform)
    float scale[4];
    #pragma unroll
    for (int r = 0; r < 4; r++) {
      float mx = fmaxf(fmaxf(st[0][r], st[1][r]), fmaxf(st[2][r], st[3][r]));
      #pragma unroll
      for (int off = 1; off < 16; off <<= 1)
        mx = fmaxf(mx, __shfl_xor(mx, off, 64));
      const float mnew = fmaxf(mrow[r], mx);
      scale[r] = __expf(mrow[r] - mnew);
      mrow[r] = mnew;
      float psum = 0.f;
      #pragma unroll
      for (int kb = 0; kb < 4; kb++) {
        float pexp = __expf(st[kb][r] - mnew);
        st[kb][r] = pexp;
        psum += pexp;
      }
      lrow[r] = lrow[r] * scale[r] + psum;   // per-lane partial over cols
    }
    #pragma unroll
    for (int nt = 0; nt < 8; nt++)
      #pragma unroll
      for (int r = 0; r < 4; r++)
        o[nt][r] *= scale[r];

    // ---- P -> per-wave LDS (A-fragment re-layout)
    #pragma unroll
    for (int kb = 0; kb < 4; kb++)
      #pragma unroll
      for (int r = 0; r < 4; r++)
        Plds[w][kg * 4 + r][kb * 16 + col] = f2bf(st[kb][r]);

    // ---- O += P V
    __builtin_amdgcn_s_setprio(1);
    #pragma unroll
    for (int kc = 0; kc < 2; kc++) {
      bf16x8 pa = ld_bf16x8(&Plds[w][col][kc * 32 + kg * 8]);
      #pragma unroll
      for (int nt = 0; nt < 8; nt++) {
        const int vrow = nt * 16 + col;                  // d
        bf16x8 vf = *(const bf16x8*)((const char*)Vtile + vrow * 256 +
            ((kvh * 128 + kc * 64 + kg * 16) ^ ((vrow & 7) << 4)));
        o[nt] = mfma16(pa, vf, o[nt]);
      }
    }
    __builtin_amdgcn_s_setprio(0);
    __syncthreads();
  }

  // ---- FIX: reduce per-lane partial l over the 16-lane col group
  float lfull[4];
  #pragma unroll
  for (int r = 0; r < 4; r++) {
    float l = lrow[r];
    #pragma unroll
    for (int off = 1; off < 16; off <<= 1)
      l += __shfl_xor(l, off, 64);
    lfull[r] = l;
  }

  // ---- merge wave-pair partials via LDS (reuse K/V tile space)
  float* Olds = (float*)Ktile;            // [4 waves][16 rows][128 d]
  float* Ml   = (float*)Vtile;            // m at [0..63], l at [64..127]
  #pragma unroll
  for (int nt = 0; nt < 8; nt++)
    #pragma unroll
    for (int r = 0; r < 4; r++)
      Olds[(w * 16 + kg * 4 + r) * 128 + nt * 16 + col] = o[nt][r];
  if (col == 0) {
    #pragma unroll
    for (int r = 0; r < 4; r++) {
      Ml[w * 16 + kg * 4 + r]      = mrow[r];
      Ml[64 + w * 16 + kg * 4 + r] = lfull[r];
    }
  }
  __syncthreads();
  if (w < 2) {
    #pragma unroll
    for (int r = 0; r < 4; r++) {
      const int row = kg * 4 + r;
      const float m1 = Ml[w * 16 + row],        l1 = Ml[64 + w * 16 + row];
      const float m2 = Ml[(w + 2) * 16 + row],  l2 = Ml[64 + (w + 2) * 16 + row];
      const float mf = fmaxf(m1, m2);
      const float w1 = __expf(m1 - mf), wgt2 = __expf(m2 - mf);
      const float inv = 1.0f / (l1 * w1 + l2 * wgt2);
      float* orow = out + (size_t)(b * S_LEN + q0 + w * 16 + row) * DH;
      #pragma unroll
      for (int nt = 0; nt < 8; nt++) {
        const float v1 = Olds[(w * 16 + row) * 128 + nt * 16 + col];
        const float v2 = Olds[((w + 2) * 16 + row) * 128 + nt * 16 + col];
        orow[nt * 16 + col] = (v1 * w1 + v2 * wgt2) * inv;
      }
    }
  }
}

// ---------------------------------------------------------------------------
extern "C" void kernel_launch(void* const* d_in, const int* in_sizes, int n_in,
                              void* d_out, int out_size, void* d_ws, size_t ws_size,
                              hipStream_t stream) {
  const float* x  = (const float*)d_in[0];
  const float* WQ = (const float*)d_in[1];
  const float* WK = (const float*)d_in[2];
  const float* WV = (const float*)d_in[3];
  float* out = (float*)d_out;

  char* ws = (char*)d_ws;
  float2*         trig = (float2*)(ws);                      // 2 MB
  unsigned short* Wt   = (unsigned short*)(ws + (2u << 20)); // 1.5 MB
  unsigned short* Qb   = (unsigned short*)(ws + (4u << 20)); // 4 MB
  unsigned short* Kb   = (unsigned short*)(ws + (8u << 20)); // 4 MB
  unsigned short* Vt   = (unsigned short*)(ws + (12u << 20));// 4 MB (ends 16MB)

  hipLaunchKernelGGL(prep_kernel, dim3(1216), dim3(256), 0, stream,
                     WQ, WK, WV, trig, Wt);
  hipLaunchKernelGGL(proj_kernel, dim3(128, 4), dim3(256), 0, stream,
                     x, Wt, trig, Qb, Kb, Vt);
  hipLaunchKernelGGL(flash_kernel, dim3(512), dim3(256), 0, stream,
                     Qb, Kb, Vt, out);
}

// Round 7
// 136.056 us; speedup vs baseline: 2.0555x; 1.0470x over previous
//
#include <hip/hip_runtime.h>
#include <hip/hip_bf16.h>
#include <stdint.h>

#define S_LEN 4096
#define E_DIM 2048
#define DH    128

typedef __bf16 bf16_t;
typedef bf16_t bf16x8 __attribute__((ext_vector_type(8)));
typedef float  f32x4  __attribute__((ext_vector_type(4)));

__device__ __forceinline__ unsigned short f2bf(float f) {
  union { float f; uint32_t u; } v; v.f = f;
  uint32_t u = v.u;
  uint32_t r = (u + 0x7fffu + ((u >> 16) & 1u)) >> 16;  // RNE
  return (unsigned short)r;
}

__device__ __forceinline__ bf16x8 ld_bf16x8(const unsigned short* p) {
  return *(const bf16x8*)p;
}

__device__ __forceinline__ f32x4 mfma16(bf16x8 a, bf16x8 b, f32x4 c) {
  return __builtin_amdgcn_mfma_f32_16x16x32_bf16(a, b, c, 0, 0, 0);
}

// async global->LDS, 16B/lane; LDS dest wave-uniform (HW adds lane*16)
__device__ __forceinline__ void gload16(const void* gsrc, void* ldst) {
  __builtin_amdgcn_global_load_lds(
      (const __attribute__((address_space(1))) uint32_t*)gsrc,
      (__attribute__((address_space(3))) uint32_t*)ldst, 16, 0, 0);
}

// ---------------------------------------------------------------------------
// prep: trig [4096][64] (blocks 0..1023) + coalesced W^T transpose (192 tiles)
// ---------------------------------------------------------------------------
__global__ __launch_bounds__(256) void prep_kernel(
    const float* __restrict__ WQ, const float* __restrict__ WK,
    const float* __restrict__ WV,
    float2* __restrict__ trig, unsigned short* __restrict__ Wt)
{
  const int bx  = blockIdx.x;
  const int tid = threadIdx.x;
  if (bx < 1024) {
    const int idx = bx * 256 + tid;            // 0 .. 262143
    const int pos = idx >> 6, p = idx & 63;
    const float freq = powf(10000.0f, -(float)p / 64.0f);
    float sv, cv;
    sincosf((float)pos * freq, &sv, &cv);
    trig[idx] = make_float2(cv, sv);
    return;
  }
  // ---- transpose W[z] (2048 k x 128 n) -> Wt[z*128+n][k], 64x64 tiles
  __shared__ float lds[64][65];
  const int t   = bx - 1024;                   // 0..191
  const int z   = t >> 6;
  const int rem = t & 63;
  const int k0  = (rem >> 1) * 64;
  const int n0  = (rem & 1) * 64;
  const float* W = (z == 0) ? WQ : ((z == 1) ? WK : WV);
  #pragma unroll
  for (int pass = 0; pass < 4; pass++) {
    const int r  = pass * 16 + (tid >> 4);
    const int c4 = (tid & 15) * 4;
    float4 v = *(const float4*)(W + (size_t)(k0 + r) * 128 + n0 + c4);
    lds[c4 + 0][r] = v.x; lds[c4 + 1][r] = v.y;
    lds[c4 + 2][r] = v.z; lds[c4 + 3][r] = v.w;
  }
  __syncthreads();
  #pragma unroll
  for (int pass = 0; pass < 4; pass++) {
    const int n  = pass * 16 + (tid >> 4);
    const int k4 = (tid & 15) * 4;
    ushort4 pk;
    pk.x = f2bf(lds[n][k4 + 0]); pk.y = f2bf(lds[n][k4 + 1]);
    pk.z = f2bf(lds[n][k4 + 2]); pk.w = f2bf(lds[n][k4 + 3]);
    *(ushort4*)(Wt + (size_t)(z * 128 + n0 + n) * E_DIM + k0 + k4) = pk;
  }
}

// ---------------------------------------------------------------------------
// proj v4: BM=128, BN=96, BK=64, 32 iters. A reg-staged f32->bf16 (T14:
// issue loads early, cvt+ds_write late). Both LDS tiles bf16, 128B rows,
// swizzle ^(row&7)<<4 on write AND read. LDS 56KB -> 2 blocks/CU.
// grid (128 mp, 4 p): same-mp blocks share x rows in the same XCD's L2.
// ---------------------------------------------------------------------------
__global__ __launch_bounds__(256, 2) void proj_kernel(
    const float* __restrict__ x, const unsigned short* __restrict__ Wt,
    const float2* __restrict__ trig,
    unsigned short* __restrict__ Qb, unsigned short* __restrict__ Kb,
    unsigned short* __restrict__ Vt)
{
  __shared__ __align__(16) uint8_t Abuf[2][128 * 128];   // bf16, 16KB/buf
  __shared__ __align__(16) uint8_t Bbuf[2][96 * 128];    // bf16, 12KB/buf

  const int tid  = threadIdx.x;
  const int lane = tid & 63, w2 = tid >> 6;
  const int wr = w2 & 1, wc = w2 >> 1;
  const int col = lane & 15, kg = lane >> 4;

  const int m0 = blockIdx.x * 128;
  const int p  = blockIdx.y;

  f32x4 acc[4][3];
  #pragma unroll
  for (int i = 0; i < 4; i++)
    #pragma unroll
    for (int j = 0; j < 3; j++) acc[i][j] = (f32x4){0.f, 0.f, 0.f, 0.f};

  // A-load geometry: per j, 4 fully-coalesced rows (1024B contiguous/instr)
  const int a_r = lane >> 4;            // row sub 0..3
  const int a_c = (lane & 15) * 4;      // float col 0..60
  // B gload16 geometry: 12 segs of 8 rows; wave w2 stages segs 3w2..3w2+2
  const int b_r  = lane >> 3;           // 0..7
  const int b_cb = (lane & 7) * 16;     // byte col 0..112

  float4 a_reg[8];

  #define ALOAD(K0)                                                           \
    do {                                                                      \
      _Pragma("unroll")                                                       \
      for (int j = 0; j < 8; j++) {                                           \
        const int row = w2 * 32 + j * 4 + a_r;                                \
        a_reg[j] = *(const float4*)(x + (size_t)(m0 + row) * E_DIM + (K0) + a_c);\
      }                                                                       \
    } while (0)

  #define BSTAGE(K0, BUF)                                                     \
    do {                                                                      \
      _Pragma("unroll")                                                       \
      for (int c = 0; c < 3; c++) {                                           \
        const int seg = w2 * 3 + c;                                           \
        const int row = seg * 8 + b_r;                                        \
        const int src = b_cb ^ ((row & 7) << 4);                              \
        gload16((const char*)Wt + ((size_t)(p * 96 + row) * E_DIM + (K0)) * 2 + src,\
                &Bbuf[BUF][seg * 1024]);                                      \
      }                                                                       \
    } while (0)

  #define AWRITE(BUF)                                                         \
    do {                                                                      \
      _Pragma("unroll")                                                       \
      for (int j = 0; j < 8; j++) {                                           \
        const int row = w2 * 32 + j * 4 + a_r;                                \
        ushort4 h;                                                            \
        h.x = f2bf(a_reg[j].x); h.y = f2bf(a_reg[j].y);                       \
        h.z = f2bf(a_reg[j].z); h.w = f2bf(a_reg[j].w);                       \
        const int dst = (a_c * 2) ^ ((row & 7) << 4);                         \
        *(ushort4*)(&Abuf[BUF][row * 128 + dst]) = h;                         \
      }                                                                       \
    } while (0)

  // prologue: stage tile 0
  ALOAD(0);
  BSTAGE(0, 0);
  AWRITE(0);
  __syncthreads();

  int cur = 0;
  for (int t = 0; t < 32; t++) {
    if (t < 31) {                       // issue next tile's loads EARLY
      ALOAD((t + 1) * 64);
      BSTAGE((t + 1) * 64, cur ^ 1);
    }

    // ---- compute tile t from buf[cur]
    __builtin_amdgcn_s_setprio(1);
    #pragma unroll
    for (int kk = 0; kk < 2; kk++) {
      bf16x8 af[4];
      #pragma unroll
      for (int i = 0; i < 4; i++) {
        const int row = wr * 64 + i * 16 + col;
        af[i] = *(const bf16x8*)(&Abuf[cur][row * 128 +
                 ((kk * 64 + kg * 16) ^ ((row & 7) << 4))]);
      }
      #pragma unroll
      for (int ns = 0; ns < 3; ns++) {
        const int n = wc * 48 + ns * 16 + col;
        bf16x8 bf = *(const bf16x8*)(&Bbuf[cur][n * 128 +
                    ((kk * 64 + kg * 16) ^ ((n & 7) << 4))]);
        #pragma unroll
        for (int i = 0; i < 4; i++)
          acc[i][ns] = mfma16(af[i], bf, acc[i][ns]);
      }
    }
    __builtin_amdgcn_s_setprio(0);

    if (t < 31) AWRITE(cur ^ 1);        // cvt + write late (loads landed)
    __syncthreads();                    // vmcnt: only 3 old B loads; lgkm drain
    cur ^= 1;
  }
  #undef ALOAD
  #undef BSTAGE
  #undef AWRITE

  // ---- epilogue: D layout col=lane&15 (n), row=(lane>>4)*4+r (m)
  #pragma unroll
  for (int i = 0; i < 4; i++) {
    const int mbase = m0 + wr * 64 + i * 16 + kg * 4;
    const int spos  = mbase & 4095;
    const int bb    = mbase >> 12;
    #pragma unroll
    for (int ns = 0; ns < 3; ns++) {
      const int n = p * 96 + wc * 48 + ns * 16 + col;
      const int z = n >> 7, d = n & 127;
      f32x4 v = acc[i][ns];
      if (z == 1) {                        // K: no rope
        #pragma unroll
        for (int r = 0; r < 4; r++)
          Kb[(size_t)(mbase + r) * DH + d] = f2bf(v[r]);
      } else {                             // Q or V: rope
        const float sgn  = (d & 1) ? 1.0f : -1.0f;
        const int   pidx = d >> 1;
        float ov[4];
        #pragma unroll
        for (int r = 0; r < 4; r++) {
          float  pv = __shfl_xor(v[r], 1, 64);
          float2 cs = trig[(spos + r) * 64 + pidx];
          ov[r] = v[r] * cs.x + sgn * pv * cs.y;
        }
        if (z == 0) {                      // Q: prescale by 1/sqrt(128)
          #pragma unroll
          for (int r = 0; r < 4; r++)
            Qb[(size_t)(mbase + r) * DH + d] =
                f2bf(ov[r] * 0.08838834764831845f);
        } else {                           // V: write transposed [b][d][s]
          ushort4 pk;
          pk.x = f2bf(ov[0]); pk.y = f2bf(ov[1]);
          pk.z = f2bf(ov[2]); pk.w = f2bf(ov[3]);
          *(ushort4*)(Vt + ((size_t)(bb * DH + d)) * S_LEN + spos) = pk;
        }
      }
    }
  }
}

// ---------------------------------------------------------------------------
// flash v4 (unchanged, passed r6): QBLK=32, KVBLK=128 over wave pairs.
// ---------------------------------------------------------------------------
__global__ __launch_bounds__(256, 2) void flash_kernel(
    const unsigned short* __restrict__ Qb, const unsigned short* __restrict__ Kb,
    const unsigned short* __restrict__ Vt, float* __restrict__ out)
{
  __shared__ __align__(16) unsigned short Ktile[128 * 128];  // [kv][d] swz
  __shared__ __align__(16) unsigned short Vtile[128 * 128];  // [d][kv] swz
  __shared__ __align__(16) unsigned short Plds[4][16][72];

  const int bid  = blockIdx.x;
  const int half = bid >> 8, rb = bid & 255;
  const int qi   = half ? (127 - (rb >> 1)) : (rb >> 1);
  const int b    = (rb & 1) | (half << 1);
  const int q0   = qi * 32;

  const int tid = threadIdx.x;
  const int lane = tid & 63, w = tid >> 6;
  const int h   = w & 1;        // q half (16 rows)
  const int kvh = w >> 1;       // kv half (64 keys)
  const int col = lane & 15, kg = lane >> 4;

  bf16x8 qf[4];
  {
    const unsigned short* qrow =
        Qb + (size_t)(b * S_LEN + q0 + h * 16 + col) * DH;
    #pragma unroll
    for (int kk = 0; kk < 4; kk++)
      qf[kk] = ld_bf16x8(qrow + kk * 32 + kg * 8);
  }

  f32x4 o[8];
  #pragma unroll
  for (int i = 0; i < 8; i++) o[i] = (f32x4){0.f, 0.f, 0.f, 0.f};
  float mrow[4] = {-1e30f, -1e30f, -1e30f, -1e30f};
  float lrow[4] = {0.f, 0.f, 0.f, 0.f};

  const char* Kbase = (const char*)(Kb + (size_t)b * S_LEN * DH);
  const char* Vbase = (const char*)(Vt + (size_t)b * DH * S_LEN);

  const int r_off = lane >> 4, colb = (lane & 15) * 16;

  for (int kv0 = 0; kv0 < q0 + 32; kv0 += 128) {
    #pragma unroll
    for (int c = 0; c < 8; c++) {
      const int row = w * 32 + c * 4 + r_off;           // kv index
      const int src = colb ^ ((row & 7) << 4);
      gload16(Kbase + (size_t)(kv0 + row) * 256 + src,
              (char*)Ktile + w * 8192 + c * 1024);
    }
    #pragma unroll
    for (int c = 0; c < 8; c++) {
      const int d   = w * 32 + c * 4 + r_off;           // head-dim index
      const int src = colb ^ ((d & 7) << 4);
      gload16(Vbase + (size_t)d * 8192 + (size_t)kv0 * 2 + src,
              (char*)Vtile + w * 8192 + c * 1024);
    }
    __syncthreads();

    // ---- S = Q K^T over this wave's 64 keys
    f32x4 st[4];
    __builtin_amdgcn_s_setprio(1);
    #pragma unroll
    for (int kb = 0; kb < 4; kb++) {
      f32x4 sacc = (f32x4){0.f, 0.f, 0.f, 0.f};
      const int krow = kvh * 64 + kb * 16 + col;
      #pragma unroll
      for (int kk = 0; kk < 4; kk++) {
        bf16x8 kf = *(const bf16x8*)((const char*)Ktile + krow * 256 +
                                     ((kk * 64 + kg * 16) ^ ((krow & 7) << 4)));
        sacc = mfma16(qf[kk], kf, sacc);
      }
      st[kb] = sacc;
    }
    __builtin_amdgcn_s_setprio(0);

    // ---- causal mask
    if (kv0 + 127 > q0) {
      #pragma unroll
      for (int kb = 0; kb < 4; kb++) {
        const int key = kv0 + kvh * 64 + kb * 16 + col;
        #pragma unroll
        for (int r = 0; r < 4; r++) {
          const int q = q0 + h * 16 + kg * 4 + r;
          if (key > q) st[kb][r] = -1e30f;
        }
      }
    }

    // ---- online softmax (16-lane group reduce; mrow group-uniform)
    float scale[4];
    #pragma unroll
    for (int r = 0; r < 4; r++) {
      float mx = fmaxf(fmaxf(st[0][r], st[1][r]), fmaxf(st[2][r], st[3][r]));
      #pragma unroll
      for (int off = 1; off < 16; off <<= 1)
        mx = fmaxf(mx, __shfl_xor(mx, off, 64));
      const float mnew = fmaxf(mrow[r], mx);
      scale[r] = __expf(mrow[r] - mnew);
      mrow[r] = mnew;
      float psum = 0.f;
      #pragma unroll
      for (int kb = 0; kb < 4; kb++) {
        float pexp = __expf(st[kb][r] - mnew);
        st[kb][r] = pexp;
        psum += pexp;
      }
      lrow[r] = lrow[r] * scale[r] + psum;   // per-lane partial over cols
    }
    #pragma unroll
    for (int nt = 0; nt < 8; nt++)
      #pragma unroll
      for (int r = 0; r < 4; r++)
        o[nt][r] *= scale[r];

    // ---- P -> per-wave LDS (A-fragment re-layout)
    #pragma unroll
    for (int kb = 0; kb < 4; kb++)
      #pragma unroll
      for (int r = 0; r < 4; r++)
        Plds[w][kg * 4 + r][kb * 16 + col] = f2bf(st[kb][r]);

    // ---- O += P V
    __builtin_amdgcn_s_setprio(1);
    #pragma unroll
    for (int kc = 0; kc < 2; kc++) {
      bf16x8 pa = ld_bf16x8(&Plds[w][col][kc * 32 + kg * 8]);
      #pragma unroll
      for (int nt = 0; nt < 8; nt++) {
        const int vrow = nt * 16 + col;                  // d
        bf16x8 vf = *(const bf16x8*)((const char*)Vtile + vrow * 256 +
            ((kvh * 128 + kc * 64 + kg * 16) ^ ((vrow & 7) << 4)));
        o[nt] = mfma16(pa, vf, o[nt]);
      }
    }
    __builtin_amdgcn_s_setprio(0);
    __syncthreads();
  }

  // ---- reduce per-lane partial l over the 16-lane col group
  float lfull[4];
  #pragma unroll
  for (int r = 0; r < 4; r++) {
    float l = lrow[r];
    #pragma unroll
    for (int off = 1; off < 16; off <<= 1)
      l += __shfl_xor(l, off, 64);
    lfull[r] = l;
  }

  // ---- merge wave-pair partials via LDS (reuse K/V tile space)
  float* Olds = (float*)Ktile;            // [4 waves][16 rows][128 d]
  float* Ml   = (float*)Vtile;            // m at [0..63], l at [64..127]
  #pragma unroll
  for (int nt = 0; nt < 8; nt++)
    #pragma unroll
    for (int r = 0; r < 4; r++)
      Olds[(w * 16 + kg * 4 + r) * 128 + nt * 16 + col] = o[nt][r];
  if (col == 0) {
    #pragma unroll
    for (int r = 0; r < 4; r++) {
      Ml[w * 16 + kg * 4 + r]      = mrow[r];
      Ml[64 + w * 16 + kg * 4 + r] = lfull[r];
    }
  }
  __syncthreads();
  if (w < 2) {
    #pragma unroll
    for (int r = 0; r < 4; r++) {
      const int row = kg * 4 + r;
      const float m1 = Ml[w * 16 + row],        l1 = Ml[64 + w * 16 + row];
      const float m2 = Ml[(w + 2) * 16 + row],  l2 = Ml[64 + (w + 2) * 16 + row];
      const float mf = fmaxf(m1, m2);
      const float w1 = __expf(m1 - mf), wgt2 = __expf(m2 - mf);
      const float inv = 1.0f / (l1 * w1 + l2 * wgt2);
      float* orow = out + (size_t)(b * S_LEN + q0 + w * 16 + row) * DH;
      #pragma unroll
      for (int nt = 0; nt < 8; nt++) {
        const float v1 = Olds[(w * 16 + row) * 128 + nt * 16 + col];
        const float v2 = Olds[((w + 2) * 16 + row) * 128 + nt * 16 + col];
        orow[nt * 16 + col] = (v1 * w1 + v2 * wgt2) * inv;
      }
    }
  }
}

// ---------------------------------------------------------------------------
extern "C" void kernel_launch(void* const* d_in, const int* in_sizes, int n_in,
                              void* d_out, int out_size, void* d_ws, size_t ws_size,
                              hipStream_t stream) {
  const float* x  = (const float*)d_in[0];
  const float* WQ = (const float*)d_in[1];
  const float* WK = (const float*)d_in[2];
  const float* WV = (const float*)d_in[3];
  float* out = (float*)d_out;

  char* ws = (char*)d_ws;
  float2*         trig = (float2*)(ws);                      // 2 MB
  unsigned short* Wt   = (unsigned short*)(ws + (2u << 20)); // 1.5 MB
  unsigned short* Qb   = (unsigned short*)(ws + (4u << 20)); // 4 MB
  unsigned short* Kb   = (unsigned short*)(ws + (8u << 20)); // 4 MB
  unsigned short* Vt   = (unsigned short*)(ws + (12u << 20));// 4 MB (ends 16MB)

  hipLaunchKernelGGL(prep_kernel, dim3(1216), dim3(256), 0, stream,
                     WQ, WK, WV, trig, Wt);
  hipLaunchKernelGGL(proj_kernel, dim3(128, 4), dim3(256), 0, stream,
                     x, Wt, trig, Qb, Kb, Vt);
  hipLaunchKernelGGL(flash_kernel, dim3(512), dim3(256), 0, stream,
                     Qb, Kb, Vt, out);
}